// Round 2
// baseline (1071.469 us; speedup 1.0000x reference)
//
#include <hip/hip_runtime.h>
#include <hip/hip_bf16.h>
#include <cstdint>
#include <cstddef>

#define B_SZ 4
#define T_SZ 1024
#define N_SZ 1024
#define HID 1024
#define NHEADS 16
#define DHEAD 64

typedef __bf16 bf16x8 __attribute__((ext_vector_type(8)));
typedef __bf16 bf16x4 __attribute__((ext_vector_type(4)));
typedef float floatx4 __attribute__((ext_vector_type(4)));

#define LDT 72  // padded LDS leading dim (64 + 8): row stride 144B -> 2-way max aliasing (free per m136)

// C[M=4096][1024] = A[M][1024] @ W[1024][1024]^T + bias.
// A, W, bias are fp32; C written as bf16 (intermediate q/k/v). fp32 accumulate.
// 128x128 block tile, BK=64, 256 threads = 4 waves, each wave 64x64 via 4x4 mfma_f32_16x16x32_bf16.
// fp32 -> bf16 conversion happens during LDS staging.
__global__ __launch_bounds__(256)
void gemm_bt_bias_f32in(const float* __restrict__ A,
                        const float* __restrict__ W,
                        const float* __restrict__ bias,
                        __hip_bfloat16* __restrict__ C)
{
    constexpr int K = HID;
    constexpr int NN = HID;
    __shared__ __align__(16) __hip_bfloat16 As[128 * LDT];
    __shared__ __align__(16) __hip_bfloat16 Bs[128 * LDT];

    const int tid  = threadIdx.x;
    const int wave = tid >> 6;
    const int lane = tid & 63;
    const int bm = blockIdx.y * 128;
    const int bn = blockIdx.x * 128;
    const int wm = (wave >> 1) * 64;
    const int wn = (wave & 1) * 64;

    floatx4 acc[4][4];
#pragma unroll
    for (int i = 0; i < 4; ++i)
#pragma unroll
        for (int j = 0; j < 4; ++j)
            acc[i][j] = (floatx4)(0.0f);

    // staging: 128x64 fp32 tile; thread reads float4, converts, writes bf16x4.
    // 16 threads cover one row (64 cols); 256 threads cover 16 rows per pass; 8 passes.
    const int lr = tid >> 4;          // 0..15
    const int lc = (tid & 15) * 4;    // 0,4,...,60

    for (int k0 = 0; k0 < K; k0 += 64) {
#pragma unroll
        for (int qq = 0; qq < 8; ++qq) {
            const int r = lr + qq * 16;
            const float4 a4 = *(const float4*)(A + (size_t)(bm + r) * K + k0 + lc);
            const float4 w4 = *(const float4*)(W + (size_t)(bn + r) * K + k0 + lc);
            bf16x4 av, wv;
            av[0] = (__bf16)a4.x; av[1] = (__bf16)a4.y; av[2] = (__bf16)a4.z; av[3] = (__bf16)a4.w;
            wv[0] = (__bf16)w4.x; wv[1] = (__bf16)w4.y; wv[2] = (__bf16)w4.z; wv[3] = (__bf16)w4.w;
            *(bf16x4*)(As + r * LDT + lc) = av;
            *(bf16x4*)(Bs + r * LDT + lc) = wv;
        }
        __syncthreads();
#pragma unroll
        for (int kk = 0; kk < 2; ++kk) {
            const int krow = kk * 32 + (lane >> 4) * 8;  // k-offset of this lane's 8 elems
            const int mrow = wm + (lane & 15);
            const int nrow = wn + (lane & 15);
            bf16x8 af[4], bfr[4];
#pragma unroll
            for (int i = 0; i < 4; ++i) {
                af[i]  = *(const bf16x8*)(As + (mrow + i * 16) * LDT + krow);
                bfr[i] = *(const bf16x8*)(Bs + (nrow + i * 16) * LDT + krow);
            }
#pragma unroll
            for (int mi = 0; mi < 4; ++mi)
#pragma unroll
                for (int ni = 0; ni < 4; ++ni)
                    acc[mi][ni] = __builtin_amdgcn_mfma_f32_16x16x32_bf16(
                        af[mi], bfr[ni], acc[mi][ni], 0, 0, 0);
        }
        __syncthreads();
    }

    // C/D layout: col = lane&15, row = (lane>>4)*4 + reg   [m89/m91-verified]
    const int crow0 = bm + wm + (lane >> 4) * 4;
    const int ccol0 = bn + wn + (lane & 15);
#pragma unroll
    for (int ni = 0; ni < 4; ++ni) {
        const int n = ccol0 + ni * 16;
        const float bias_f = bias[n];
#pragma unroll
        for (int mi = 0; mi < 4; ++mi) {
#pragma unroll
            for (int r = 0; r < 4; ++r) {
                const int m = crow0 + mi * 16 + r;
                C[(size_t)m * NN + n] = __float2bfloat16(acc[mi][ni][r] + bias_f);
            }
        }
    }
}

// Causal attention, correctness-first VALU version.
// q/k/v are bf16 (intermediates); output fp32.
// One wave per (b,h,t) row; 4 waves / block; grid = B*NHEADS*T/4 = 16384.
__global__ __launch_bounds__(256)
void attn_causal(const __hip_bfloat16* __restrict__ q,
                 const __hip_bfloat16* __restrict__ k,
                 const __hip_bfloat16* __restrict__ v,
                 float* __restrict__ out)
{
    __shared__ __align__(16) float qs[4][64];
    __shared__ __align__(16) float ps[4][1024];

    const int wave = threadIdx.x >> 6;
    const int lane = threadIdx.x & 63;
    const int row_id = blockIdx.x * 4 + wave;     // ((b*NHEADS + h)*T + t)
    const int t  = row_id & (T_SZ - 1);
    const int bh = row_id >> 10;
    const int h  = bh & (NHEADS - 1);
    const int b  = bh >> 4;

    const size_t qoff = (size_t)(b * T_SZ + t) * HID + h * DHEAD;
    qs[wave][lane] = __bfloat162float(q[qoff + lane]);
    __syncthreads();  // uniform: every wave executes exactly once

    const int nchunks = (t >> 6) + 1;
    float mloc = -INFINITY;
    const __hip_bfloat16* kbase = k + (size_t)b * N_SZ * HID + h * DHEAD;

    // pass 1: scores -> ps, track max
    for (int j = 0; j < nchunks; ++j) {
        const int n = j * 64 + lane;
        float s = -INFINITY;
        if (n <= t) {
            const __hip_bfloat16* krow = kbase + (size_t)n * HID;
            float a = 0.f;
#pragma unroll
            for (int d = 0; d < 64; d += 8) {
                const bf16x8 kv = *(const bf16x8*)(krow + d);
                const float4 q0 = *(const float4*)&qs[wave][d];
                const float4 q1 = *(const float4*)&qs[wave][d + 4];
                a += (float)kv[0] * q0.x + (float)kv[1] * q0.y +
                     (float)kv[2] * q0.z + (float)kv[3] * q0.w +
                     (float)kv[4] * q1.x + (float)kv[5] * q1.y +
                     (float)kv[6] * q1.z + (float)kv[7] * q1.w;
            }
            s = a * 0.125f;  // 1/sqrt(64)
        }
        ps[wave][j * 64 + lane] = s;
        mloc = fmaxf(mloc, s);
    }
#pragma unroll
    for (int off = 32; off > 0; off >>= 1)
        mloc = fmaxf(mloc, __shfl_xor(mloc, off, 64));

    __threadfence_block();  // order ps writes vs re-reads (wave-private LDS)

    // pass 2: exponentiate in place, sum
    float lsum = 0.f;
    for (int j = 0; j < nchunks; ++j) {
        const float s = ps[wave][j * 64 + lane];
        const float e = __expf(s - mloc);   // masked lanes: exp(-inf)=0
        ps[wave][j * 64 + lane] = e;
        lsum += e;
    }
#pragma unroll
    for (int off = 32; off > 0; off >>= 1)
        lsum += __shfl_xor(lsum, off, 64);
    const float inv_l = 1.0f / lsum;

    __threadfence_block();

    // pass 3: o[d=lane] = sum_n p[n] * v[n][d]
    const __hip_bfloat16* vbase = v + (size_t)b * N_SZ * HID + h * DHEAD + lane;
    float o = 0.f;
    const int tot = t + 1;
    int n = 0;
    for (; n + 4 <= tot; n += 4) {
        const float4 p4 = *(const float4*)&ps[wave][n];  // broadcast read
        const float v0 = __bfloat162float(vbase[(size_t)(n + 0) * HID]);
        const float v1 = __bfloat162float(vbase[(size_t)(n + 1) * HID]);
        const float v2 = __bfloat162float(vbase[(size_t)(n + 2) * HID]);
        const float v3 = __bfloat162float(vbase[(size_t)(n + 3) * HID]);
        o += p4.x * v0 + p4.y * v1 + p4.z * v2 + p4.w * v3;
    }
    for (; n < tot; ++n)
        o += ps[wave][n] * __bfloat162float(vbase[(size_t)n * HID]);

    out[qoff + lane] = o * inv_l;
}

extern "C" void kernel_launch(void* const* d_in, const int* in_sizes, int n_in,
                              void* d_out, int out_size, void* d_ws, size_t ws_size,
                              hipStream_t stream) {
    const float* x   = (const float*)d_in[0];
    const float* enc = (const float*)d_in[1];
    const float* Wq  = (const float*)d_in[2];
    const float* bq  = (const float*)d_in[3];
    const float* Wk  = (const float*)d_in[4];
    const float* bk  = (const float*)d_in[5];
    const float* Wv  = (const float*)d_in[6];
    const float* bv  = (const float*)d_in[7];
    float* out = (float*)d_out;

    char* ws = (char*)d_ws;
    __hip_bfloat16* q_ws = (__hip_bfloat16*)(ws);
    __hip_bfloat16* k_ws = (__hip_bfloat16*)(ws + (size_t)8 * 1024 * 1024);
    __hip_bfloat16* v_ws = (__hip_bfloat16*)(ws + (size_t)16 * 1024 * 1024);

    const dim3 gg(HID / 128, (B_SZ * T_SZ) / 128);  // (8, 32)
    const dim3 blk(256);
    gemm_bt_bias_f32in<<<gg, blk, 0, stream>>>(x,   Wq, bq, q_ws);
    gemm_bt_bias_f32in<<<gg, blk, 0, stream>>>(enc, Wk, bk, k_ws);
    gemm_bt_bias_f32in<<<gg, blk, 0, stream>>>(enc, Wv, bv, v_ws);

    attn_causal<<<dim3((B_SZ * NHEADS * T_SZ) / 4), blk, 0, stream>>>(q_ws, k_ws, v_ws, out);
}

// Round 3
// 266.131 us; speedup vs baseline: 4.0261x; 4.0261x over previous
//
#include <hip/hip_runtime.h>
#include <hip/hip_bf16.h>
#include <cstdint>
#include <cstddef>

#define B_SZ 4
#define T_SZ 1024
#define N_SZ 1024
#define HID 1024
#define NHEADS 16
#define DHEAD 64

typedef __bf16 bf16x8 __attribute__((ext_vector_type(8)));
typedef __bf16 bf16x4 __attribute__((ext_vector_type(4)));
typedef float floatx4 __attribute__((ext_vector_type(4)));

#define LDT 72  // padded LDS leading dim: 144B row stride -> worst 2-way aliasing on b128 frag reads (free per m136)

// ---------------------------------------------------------------------------
// C[M=4096][1024] = A[M][1024] @ W[1024][1024]^T + bias.
// A, W, bias fp32; C written bf16 (intermediate q/k/v). fp32 accumulate.
// 128x128 tile, BK=64, 4 waves, 4x4 mfma_f32_16x16x32_bf16 per wave.
// ---------------------------------------------------------------------------
__global__ __launch_bounds__(256)
void gemm_bt_bias_f32in(const float* __restrict__ A,
                        const float* __restrict__ W,
                        const float* __restrict__ bias,
                        __hip_bfloat16* __restrict__ C)
{
    constexpr int K = HID;
    constexpr int NN = HID;
    __shared__ __align__(16) __hip_bfloat16 As[128 * LDT];
    __shared__ __align__(16) __hip_bfloat16 Bs[128 * LDT];

    const int tid  = threadIdx.x;
    const int wave = tid >> 6;
    const int lane = tid & 63;
    const int bm = blockIdx.y * 128;
    const int bn = blockIdx.x * 128;
    const int wm = (wave >> 1) * 64;
    const int wn = (wave & 1) * 64;

    floatx4 acc[4][4];
#pragma unroll
    for (int i = 0; i < 4; ++i)
#pragma unroll
        for (int j = 0; j < 4; ++j)
            acc[i][j] = (floatx4)(0.0f);

    const int lr = tid >> 4;          // 0..15
    const int lc = (tid & 15) * 4;    // 0,4,...,60

    for (int k0 = 0; k0 < K; k0 += 64) {
#pragma unroll
        for (int qq = 0; qq < 8; ++qq) {
            const int r = lr + qq * 16;
            const float4 a4 = *(const float4*)(A + (size_t)(bm + r) * K + k0 + lc);
            const float4 w4 = *(const float4*)(W + (size_t)(bn + r) * K + k0 + lc);
            bf16x4 av, wv;
            av[0] = (__bf16)a4.x; av[1] = (__bf16)a4.y; av[2] = (__bf16)a4.z; av[3] = (__bf16)a4.w;
            wv[0] = (__bf16)w4.x; wv[1] = (__bf16)w4.y; wv[2] = (__bf16)w4.z; wv[3] = (__bf16)w4.w;
            *(bf16x4*)(As + r * LDT + lc) = av;
            *(bf16x4*)(Bs + r * LDT + lc) = wv;
        }
        __syncthreads();
#pragma unroll
        for (int kk = 0; kk < 2; ++kk) {
            const int krow = kk * 32 + (lane >> 4) * 8;
            const int mrow = wm + (lane & 15);
            const int nrow = wn + (lane & 15);
            bf16x8 af[4], bfr[4];
#pragma unroll
            for (int i = 0; i < 4; ++i) {
                af[i]  = *(const bf16x8*)(As + (mrow + i * 16) * LDT + krow);
                bfr[i] = *(const bf16x8*)(Bs + (nrow + i * 16) * LDT + krow);
            }
#pragma unroll
            for (int mi = 0; mi < 4; ++mi)
#pragma unroll
                for (int ni = 0; ni < 4; ++ni)
                    acc[mi][ni] = __builtin_amdgcn_mfma_f32_16x16x32_bf16(
                        af[mi], bfr[ni], acc[mi][ni], 0, 0, 0);
        }
        __syncthreads();
    }

    // C/D layout: col = lane&15, row = (lane>>4)*4 + reg   [m89/m91-verified]
    const int crow0 = bm + wm + (lane >> 4) * 4;
    const int ccol0 = bn + wn + (lane & 15);
#pragma unroll
    for (int ni = 0; ni < 4; ++ni) {
        const int n = ccol0 + ni * 16;
        const float bias_f = bias[n];
#pragma unroll
        for (int mi = 0; mi < 4; ++mi) {
#pragma unroll
            for (int r = 0; r < 4; ++r) {
                const int m = crow0 + mi * 16 + r;
                C[(size_t)m * NN + n] = __float2bfloat16(acc[mi][ni][r] + bias_f);
            }
        }
    }
}

// ---------------------------------------------------------------------------
// Flash attention, MFMA version.
// Block: 64 q-rows of one (b,h); 4 waves x 16 q-rows. Iterate 64-key tiles
// with online softmax. q/k/v bf16 in ws, output fp32.
//   S tile:  A=Q[m][d] frag, B=K[n][d] frag (=K^T), C/D: col=n(lane&15),
//            row=quad*4+reg  -> row stats reduce across 16-lane groups.
//   P->LDS (C/D layout -> [m][n]) -> A-frag for PV.
//   V staged transposed Vt[d][n] so PV B-frag is a contiguous b128 read.
// ---------------------------------------------------------------------------
__global__ __launch_bounds__(256)
void attn_flash_mfma(const __bf16* __restrict__ q,
                     const __bf16* __restrict__ k,
                     const __bf16* __restrict__ v,
                     float* __restrict__ out)
{
    __shared__ __align__(16) __bf16 Qs[64 * LDT];       // [qrow][d]
    __shared__ __align__(16) __bf16 Ks[64 * LDT];       // [n][d]
    __shared__ __align__(16) __bf16 Vt[64 * LDT];       // [d][n]
    __shared__ __align__(16) __bf16 Ps[4][16 * LDT];    // per-wave P [qrow16][n]

    const int tid  = threadIdx.x;
    const int wave = tid >> 6;
    const int lane = tid & 63;
    const int l15  = lane & 15;
    const int quad = lane >> 4;

    const int bx = blockIdx.x;           // 0..1023
    const int tt = 15 - (bx & 15);       // longest-job-first over t-tiles
    const int bh = bx >> 4;              // 0..63
    const int h  = bh & (NHEADS - 1);
    const int b  = bh >> 4;
    const int t0 = tt * 64;

    const __bf16* qbase = q + ((size_t)(b * T_SZ + t0)) * HID + h * DHEAD;
    const __bf16* kbase = k + (size_t)b * N_SZ * HID + h * DHEAD;
    const __bf16* vbase = v + (size_t)b * N_SZ * HID + h * DHEAD;

    // ---- stage Q tile (64x64) ----
    {
        const int r0 = tid >> 3;             // 0..31
        const int c  = (tid & 7) * 8;
#pragma unroll
        for (int p = 0; p < 2; ++p) {
            const int r = r0 + p * 32;
            *(bf16x8*)(Qs + r * LDT + c) = *(const bf16x8*)(qbase + (size_t)r * HID + c);
        }
    }

    // online-softmax state (per lane: rows quad*4+r of this wave's 16)
    float mrun[4], lrun[4];
    floatx4 oacc[4];
#pragma unroll
    for (int r = 0; r < 4; ++r) { mrun[r] = -INFINITY; lrun[r] = 0.f; }
#pragma unroll
    for (int nd = 0; nd < 4; ++nd) oacc[nd] = (floatx4)(0.0f);

    const int ntiles = tt + 1;
    for (int it = 0; it < ntiles; ++it) {
        const int n0 = it * 64;
        __syncthreads();   // prior PV reads of Ks/Vt complete (and Q staged, it=0)

        // ---- stage K tile [n][d] ----
        {
            const int r0 = tid >> 3;
            const int c  = (tid & 7) * 8;
#pragma unroll
            for (int p = 0; p < 2; ++p) {
                const int r = r0 + p * 32;
                *(bf16x8*)(Ks + r * LDT + c) =
                    *(const bf16x8*)(kbase + (size_t)(n0 + r) * HID + c);
            }
        }
        // ---- stage V tile transposed Vt[d][n] ----
        {
            const int n  = tid & 63;
            const int d0 = (tid >> 6) * 8;
#pragma unroll
            for (int p = 0; p < 2; ++p) {
                const int dp = d0 + p * 32;
                const bf16x8 vv = *(const bf16x8*)(vbase + (size_t)(n0 + n) * HID + dp);
#pragma unroll
                for (int j = 0; j < 8; ++j)
                    Vt[(dp + j) * LDT + n] = vv[j];
            }
        }
        __syncthreads();

        // ---- S = Q @ K^T (per wave: 16 rows x 64 cols) ----
        floatx4 sacc[4];
#pragma unroll
        for (int ni = 0; ni < 4; ++ni) sacc[ni] = (floatx4)(0.0f);
#pragma unroll
        for (int kk = 0; kk < 2; ++kk) {
            const int ko = kk * 32 + quad * 8;
            const bf16x8 aq = *(const bf16x8*)(Qs + (wave * 16 + l15) * LDT + ko);
#pragma unroll
            for (int ni = 0; ni < 4; ++ni) {
                const bf16x8 bk = *(const bf16x8*)(Ks + (ni * 16 + l15) * LDT + ko);
                sacc[ni] = __builtin_amdgcn_mfma_f32_16x16x32_bf16(aq, bk, sacc[ni], 0, 0, 0);
            }
        }

        // ---- scale + causal mask (diagonal tile only) + row max ----
        const bool diag = (it == tt);
        float rmax[4] = {-INFINITY, -INFINITY, -INFINITY, -INFINITY};
#pragma unroll
        for (int ni = 0; ni < 4; ++ni) {
            const int ncol = ni * 16 + l15;          // col within 64-tile
#pragma unroll
            for (int r = 0; r < 4; ++r) {
                float s = sacc[ni][r] * 0.125f;       // 1/sqrt(64)
                if (diag) {
                    const int trow = wave * 16 + quad * 4 + r;
                    if (ncol > trow) s = -INFINITY;
                }
                sacc[ni][r] = s;
                rmax[r] = fmaxf(rmax[r], s);
            }
        }
#pragma unroll
        for (int off = 1; off < 16; off <<= 1)
#pragma unroll
            for (int r = 0; r < 4; ++r)
                rmax[r] = fmaxf(rmax[r], __shfl_xor(rmax[r], off, 64));

        // ---- online update: alpha, P=exp(S-mnew), row sum ----
        float alpha[4], rsum[4];
#pragma unroll
        for (int r = 0; r < 4; ++r) {
            const float mnew = fmaxf(mrun[r], rmax[r]);
            alpha[r] = __expf(mrun[r] - mnew);       // exp(-inf)=0 on first tile
            mrun[r]  = mnew;
            rsum[r]  = 0.f;
        }
        __bf16* pw = &Ps[wave][0];
#pragma unroll
        for (int ni = 0; ni < 4; ++ni) {
#pragma unroll
            for (int r = 0; r < 4; ++r) {
                const float p = __expf(sacc[ni][r] - mrun[r]);
                rsum[r] += p;
                pw[(quad * 4 + r) * LDT + ni * 16 + l15] = (__bf16)p;
            }
        }
#pragma unroll
        for (int off = 1; off < 16; off <<= 1)
#pragma unroll
            for (int r = 0; r < 4; ++r)
                rsum[r] += __shfl_xor(rsum[r], off, 64);
#pragma unroll
        for (int r = 0; r < 4; ++r)
            lrun[r] = lrun[r] * alpha[r] + rsum[r];
#pragma unroll
        for (int nd = 0; nd < 4; ++nd)
#pragma unroll
            for (int r = 0; r < 4; ++r)
                oacc[nd][r] *= alpha[r];

        __syncthreads();   // P visible (orders wave's ds_write -> ds_read too)

        // ---- O += P @ V ----
#pragma unroll
        for (int kk = 0; kk < 2; ++kk) {
            const int ko = kk * 32 + quad * 8;
            const bf16x8 ap = *(const bf16x8*)(pw + l15 * LDT + ko);
#pragma unroll
            for (int nd = 0; nd < 4; ++nd) {
                const bf16x8 bv = *(const bf16x8*)(Vt + (nd * 16 + l15) * LDT + ko);
                oacc[nd] = __builtin_amdgcn_mfma_f32_16x16x32_bf16(ap, bv, oacc[nd], 0, 0, 0);
            }
        }
    }

    // ---- epilogue: normalize, store fp32 ----
    float invl[4];
#pragma unroll
    for (int r = 0; r < 4; ++r) invl[r] = 1.0f / lrun[r];
#pragma unroll
    for (int nd = 0; nd < 4; ++nd) {
#pragma unroll
        for (int r = 0; r < 4; ++r) {
            const int trow = t0 + wave * 16 + quad * 4 + r;
            out[(size_t)(b * T_SZ + trow) * HID + h * DHEAD + nd * 16 + l15] =
                oacc[nd][r] * invl[r];
        }
    }
}

extern "C" void kernel_launch(void* const* d_in, const int* in_sizes, int n_in,
                              void* d_out, int out_size, void* d_ws, size_t ws_size,
                              hipStream_t stream) {
    const float* x   = (const float*)d_in[0];
    const float* enc = (const float*)d_in[1];
    const float* Wq  = (const float*)d_in[2];
    const float* bq  = (const float*)d_in[3];
    const float* Wk  = (const float*)d_in[4];
    const float* bk  = (const float*)d_in[5];
    const float* Wv  = (const float*)d_in[6];
    const float* bv  = (const float*)d_in[7];
    float* out = (float*)d_out;

    char* ws = (char*)d_ws;
    __hip_bfloat16* q_ws = (__hip_bfloat16*)(ws);
    __hip_bfloat16* k_ws = (__hip_bfloat16*)(ws + (size_t)8 * 1024 * 1024);
    __hip_bfloat16* v_ws = (__hip_bfloat16*)(ws + (size_t)16 * 1024 * 1024);

    const dim3 gg(HID / 128, (B_SZ * T_SZ) / 128);  // (8, 32)
    const dim3 blk(256);
    gemm_bt_bias_f32in<<<gg, blk, 0, stream>>>(x,   Wq, bq, q_ws);
    gemm_bt_bias_f32in<<<gg, blk, 0, stream>>>(enc, Wk, bk, k_ws);
    gemm_bt_bias_f32in<<<gg, blk, 0, stream>>>(enc, Wv, bv, v_ws);

    attn_flash_mfma<<<dim3(B_SZ * NHEADS * (T_SZ / 64)), blk, 0, stream>>>(
        (const __bf16*)q_ws, (const __bf16*)k_ws, (const __bf16*)v_ws, out);
}

// Round 4
// 214.583 us; speedup vs baseline: 4.9933x; 1.2402x over previous
//
#include <hip/hip_runtime.h>
#include <hip/hip_bf16.h>
#include <cstdint>
#include <cstddef>

#define B_SZ 4
#define T_SZ 1024
#define N_SZ 1024
#define HID 1024
#define NHEADS 16
#define DHEAD 64

typedef __bf16 bf16x8 __attribute__((ext_vector_type(8)));
typedef __bf16 bf16x4 __attribute__((ext_vector_type(4)));
typedef float floatx4 __attribute__((ext_vector_type(4)));

#define LDT 72  // padded LDS leading dim for attn / fallback gemm

// global -> LDS async copy, 16B per lane. LDS dest must be wave-uniform base
// + lane*16 (m104/m108); pointers cast via uintptr_t (CK-style) to addrspaces.
__device__ __forceinline__ void async_copy16(const void* gsrc, void* ldst) {
    __builtin_amdgcn_global_load_lds(
        (const __attribute__((address_space(1))) void*)(uintptr_t)gsrc,
        (__attribute__((address_space(3))) void*)(uintptr_t)ldst, 16, 0, 0);
}

// ---------------------------------------------------------------------------
// Convert fp32 -> bf16 for x(4M), enc(4M), Wq/Wk/Wv(1M each). 2048 elems/block.
// blocks: [0,2048) x | [2048,4096) enc | [4096,4608) Wq | [4608,5120) Wk | [5120,5632) Wv
// ---------------------------------------------------------------------------
__global__ __launch_bounds__(256)
void cvt5_f32_bf16(const float* __restrict__ x, const float* __restrict__ enc,
                   const float* __restrict__ wq, const float* __restrict__ wk,
                   const float* __restrict__ wv,
                   __bf16* __restrict__ xb, __bf16* __restrict__ eb,
                   __bf16* __restrict__ wqb, __bf16* __restrict__ wkb,
                   __bf16* __restrict__ wvb)
{
    const int bx = blockIdx.x;
    const float* s; __bf16* d; int base;
    if (bx < 2048)      { s = x;   d = xb;  base = bx; }
    else if (bx < 4096) { s = enc; d = eb;  base = bx - 2048; }
    else if (bx < 4608) { s = wq;  d = wqb; base = bx - 4096; }
    else if (bx < 5120) { s = wk;  d = wkb; base = bx - 4608; }
    else                { s = wv;  d = wvb; base = bx - 5120; }
    const size_t off = (size_t)base * 2048 + (size_t)threadIdx.x * 8;
    const float4 a = *(const float4*)(s + off);
    const float4 b = *(const float4*)(s + off + 4);
    bf16x8 o;
    o[0] = (__bf16)a.x; o[1] = (__bf16)a.y; o[2] = (__bf16)a.z; o[3] = (__bf16)a.w;
    o[4] = (__bf16)b.x; o[5] = (__bf16)b.y; o[6] = (__bf16)b.z; o[7] = (__bf16)b.w;
    *(bf16x8*)(d + off) = o;
}

// ---------------------------------------------------------------------------
// Fused QKV GEMM, m97 structure: C = A @ W^T + bias, all bf16 (bias fp32).
// gridDim = (8, 32, 3); z selects {A,W,bias,C}. 128x128 tile, BK=64,
// unpadded LDS tiles staged via global_load_lds width=16; 4 waves x 4x4 MFMA.
// ---------------------------------------------------------------------------
__global__ __launch_bounds__(256)
void gemm3_bt_bias(const __bf16* __restrict__ xb, const __bf16* __restrict__ eb,
                   const __bf16* __restrict__ wqb, const __bf16* __restrict__ wkb,
                   const __bf16* __restrict__ wvb,
                   const float* __restrict__ bq, const float* __restrict__ bk,
                   const float* __restrict__ bv,
                   __bf16* __restrict__ qo, __bf16* __restrict__ ko,
                   __bf16* __restrict__ vo)
{
    constexpr int K = HID;
    __shared__ __align__(16) __bf16 As[128 * 64];  // unpadded: global_load_lds layout
    __shared__ __align__(16) __bf16 Bs[128 * 64];

    const __bf16* A; const __bf16* W; const float* bias; __bf16* C;
    if (blockIdx.z == 0)      { A = xb; W = wqb; bias = bq; C = qo; }
    else if (blockIdx.z == 1) { A = eb; W = wkb; bias = bk; C = ko; }
    else                      { A = eb; W = wvb; bias = bv; C = vo; }

    const int tid  = threadIdx.x;
    const int wave = tid >> 6;
    const int lane = tid & 63;
    const int l15  = lane & 15;
    const int quad = lane >> 4;
    const int bm = blockIdx.y * 128;
    const int bn = blockIdx.x * 128;
    const int wm = (wave >> 1) * 64;
    const int wn = (wave & 1) * 64;

    floatx4 acc[4][4];
#pragma unroll
    for (int i = 0; i < 4; ++i)
#pragma unroll
        for (int j = 0; j < 4; ++j)
            acc[i][j] = (floatx4)(0.0f);

    // staging map: elem f = p*2048 + tid*8  ->  row r = p*32 + tid>>3, col c = (tid&7)*8
    const int sr = tid >> 3;
    const int sc = (tid & 7) * 8;

    for (int k0 = 0; k0 < K; k0 += 64) {
#pragma unroll
        for (int p = 0; p < 4; ++p) {
            const int r = p * 32 + sr;
            async_copy16(A + (size_t)(bm + r) * K + k0 + sc,
                         (char*)As + p * 4096 + tid * 16);
            async_copy16(W + (size_t)(bn + r) * K + k0 + sc,
                         (char*)Bs + p * 4096 + tid * 16);
        }
        __syncthreads();   // compiler emits vmcnt(0) drain before barrier
#pragma unroll
        for (int kk = 0; kk < 2; ++kk) {
            const int ko_ = kk * 32 + quad * 8;
            bf16x8 af[4], bfr[4];
#pragma unroll
            for (int i = 0; i < 4; ++i) {
                af[i]  = *(const bf16x8*)(As + (wm + i * 16 + l15) * 64 + ko_);
                bfr[i] = *(const bf16x8*)(Bs + (wn + i * 16 + l15) * 64 + ko_);
            }
#pragma unroll
            for (int mi = 0; mi < 4; ++mi)
#pragma unroll
                for (int ni = 0; ni < 4; ++ni)
                    acc[mi][ni] = __builtin_amdgcn_mfma_f32_16x16x32_bf16(
                        af[mi], bfr[ni], acc[mi][ni], 0, 0, 0);
        }
        __syncthreads();
    }

    // C/D layout: col = lane&15, row = (lane>>4)*4 + reg   [m89/m91-verified]
    const int crow0 = bm + wm + quad * 4;
    const int ccol0 = bn + wn + l15;
#pragma unroll
    for (int ni = 0; ni < 4; ++ni) {
        const int n = ccol0 + ni * 16;
        const float bias_f = bias[n];
#pragma unroll
        for (int mi = 0; mi < 4; ++mi) {
#pragma unroll
            for (int r = 0; r < 4; ++r) {
                const int m = crow0 + mi * 16 + r;
                C[(size_t)m * HID + n] = (__bf16)(acc[mi][ni][r] + bias_f);
            }
        }
    }
}

// ---------------------------------------------------------------------------
// Fallback GEMM (fp32 inputs, staged+converted through LDS) for small ws.
// ---------------------------------------------------------------------------
__global__ __launch_bounds__(256)
void gemm_bt_bias_f32in(const float* __restrict__ A,
                        const float* __restrict__ W,
                        const float* __restrict__ bias,
                        __hip_bfloat16* __restrict__ C)
{
    constexpr int K = HID;
    __shared__ __align__(16) __hip_bfloat16 As[128 * LDT];
    __shared__ __align__(16) __hip_bfloat16 Bs[128 * LDT];

    const int tid  = threadIdx.x;
    const int wave = tid >> 6;
    const int lane = tid & 63;
    const int bm = blockIdx.y * 128;
    const int bn = blockIdx.x * 128;
    const int wm = (wave >> 1) * 64;
    const int wn = (wave & 1) * 64;

    floatx4 acc[4][4];
#pragma unroll
    for (int i = 0; i < 4; ++i)
#pragma unroll
        for (int j = 0; j < 4; ++j)
            acc[i][j] = (floatx4)(0.0f);

    const int lr = tid >> 4;
    const int lc = (tid & 15) * 4;

    for (int k0 = 0; k0 < K; k0 += 64) {
#pragma unroll
        for (int qq = 0; qq < 8; ++qq) {
            const int r = lr + qq * 16;
            const float4 a4 = *(const float4*)(A + (size_t)(bm + r) * K + k0 + lc);
            const float4 w4 = *(const float4*)(W + (size_t)(bn + r) * K + k0 + lc);
            bf16x4 av, wv;
            av[0] = (__bf16)a4.x; av[1] = (__bf16)a4.y; av[2] = (__bf16)a4.z; av[3] = (__bf16)a4.w;
            wv[0] = (__bf16)w4.x; wv[1] = (__bf16)w4.y; wv[2] = (__bf16)w4.z; wv[3] = (__bf16)w4.w;
            *(bf16x4*)(As + r * LDT + lc) = av;
            *(bf16x4*)(Bs + r * LDT + lc) = wv;
        }
        __syncthreads();
#pragma unroll
        for (int kk = 0; kk < 2; ++kk) {
            const int krow = kk * 32 + (lane >> 4) * 8;
            const int mrow = wm + (lane & 15);
            const int nrow = wn + (lane & 15);
            bf16x8 af[4], bfr[4];
#pragma unroll
            for (int i = 0; i < 4; ++i) {
                af[i]  = *(const bf16x8*)(As + (mrow + i * 16) * LDT + krow);
                bfr[i] = *(const bf16x8*)(Bs + (nrow + i * 16) * LDT + krow);
            }
#pragma unroll
            for (int mi = 0; mi < 4; ++mi)
#pragma unroll
                for (int ni = 0; ni < 4; ++ni)
                    acc[mi][ni] = __builtin_amdgcn_mfma_f32_16x16x32_bf16(
                        af[mi], bfr[ni], acc[mi][ni], 0, 0, 0);
        }
        __syncthreads();
    }

    const int crow0 = bm + wm + (lane >> 4) * 4;
    const int ccol0 = bn + wn + (lane & 15);
#pragma unroll
    for (int ni = 0; ni < 4; ++ni) {
        const int n = ccol0 + ni * 16;
        const float bias_f = bias[n];
#pragma unroll
        for (int mi = 0; mi < 4; ++mi) {
#pragma unroll
            for (int r = 0; r < 4; ++r) {
                const int m = crow0 + mi * 16 + r;
                C[(size_t)m * HID + n] = __float2bfloat16(acc[mi][ni][r] + bias_f);
            }
        }
    }
}

// ---------------------------------------------------------------------------
// Flash attention, MFMA (unchanged from R3; 76 us, next round's target).
// ---------------------------------------------------------------------------
__global__ __launch_bounds__(256)
void attn_flash_mfma(const __bf16* __restrict__ q,
                     const __bf16* __restrict__ k,
                     const __bf16* __restrict__ v,
                     float* __restrict__ out)
{
    __shared__ __align__(16) __bf16 Qs[64 * LDT];       // [qrow][d]
    __shared__ __align__(16) __bf16 Ks[64 * LDT];       // [n][d]
    __shared__ __align__(16) __bf16 Vt[64 * LDT];       // [d][n]
    __shared__ __align__(16) __bf16 Ps[4][16 * LDT];    // per-wave P [qrow16][n]

    const int tid  = threadIdx.x;
    const int wave = tid >> 6;
    const int lane = tid & 63;
    const int l15  = lane & 15;
    const int quad = lane >> 4;

    const int bx = blockIdx.x;
    const int tt = 15 - (bx & 15);       // longest-job-first over t-tiles
    const int bh = bx >> 4;
    const int h  = bh & (NHEADS - 1);
    const int b  = bh >> 4;
    const int t0 = tt * 64;

    const __bf16* qbase = q + ((size_t)(b * T_SZ + t0)) * HID + h * DHEAD;
    const __bf16* kbase = k + (size_t)b * N_SZ * HID + h * DHEAD;
    const __bf16* vbase = v + (size_t)b * N_SZ * HID + h * DHEAD;

    {
        const int r0 = tid >> 3;
        const int c  = (tid & 7) * 8;
#pragma unroll
        for (int p = 0; p < 2; ++p) {
            const int r = r0 + p * 32;
            *(bf16x8*)(Qs + r * LDT + c) = *(const bf16x8*)(qbase + (size_t)r * HID + c);
        }
    }

    float mrun[4], lrun[4];
    floatx4 oacc[4];
#pragma unroll
    for (int r = 0; r < 4; ++r) { mrun[r] = -INFINITY; lrun[r] = 0.f; }
#pragma unroll
    for (int nd = 0; nd < 4; ++nd) oacc[nd] = (floatx4)(0.0f);

    const int ntiles = tt + 1;
    for (int it = 0; it < ntiles; ++it) {
        const int n0 = it * 64;
        __syncthreads();

        {
            const int r0 = tid >> 3;
            const int c  = (tid & 7) * 8;
#pragma unroll
            for (int p = 0; p < 2; ++p) {
                const int r = r0 + p * 32;
                *(bf16x8*)(Ks + r * LDT + c) =
                    *(const bf16x8*)(kbase + (size_t)(n0 + r) * HID + c);
            }
        }
        {
            const int n  = tid & 63;
            const int d0 = (tid >> 6) * 8;
#pragma unroll
            for (int p = 0; p < 2; ++p) {
                const int dp = d0 + p * 32;
                const bf16x8 vv = *(const bf16x8*)(vbase + (size_t)(n0 + n) * HID + dp);
#pragma unroll
                for (int j = 0; j < 8; ++j)
                    Vt[(dp + j) * LDT + n] = vv[j];
            }
        }
        __syncthreads();

        floatx4 sacc[4];
#pragma unroll
        for (int ni = 0; ni < 4; ++ni) sacc[ni] = (floatx4)(0.0f);
#pragma unroll
        for (int kk = 0; kk < 2; ++kk) {
            const int ko = kk * 32 + quad * 8;
            const bf16x8 aq = *(const bf16x8*)(Qs + (wave * 16 + l15) * LDT + ko);
#pragma unroll
            for (int ni = 0; ni < 4; ++ni) {
                const bf16x8 bk = *(const bf16x8*)(Ks + (ni * 16 + l15) * LDT + ko);
                sacc[ni] = __builtin_amdgcn_mfma_f32_16x16x32_bf16(aq, bk, sacc[ni], 0, 0, 0);
            }
        }

        const bool diag = (it == tt);
        float rmax[4] = {-INFINITY, -INFINITY, -INFINITY, -INFINITY};
#pragma unroll
        for (int ni = 0; ni < 4; ++ni) {
            const int ncol = ni * 16 + l15;
#pragma unroll
            for (int r = 0; r < 4; ++r) {
                float s = sacc[ni][r] * 0.125f;
                if (diag) {
                    const int trow = wave * 16 + quad * 4 + r;
                    if (ncol > trow) s = -INFINITY;
                }
                sacc[ni][r] = s;
                rmax[r] = fmaxf(rmax[r], s);
            }
        }
#pragma unroll
        for (int off = 1; off < 16; off <<= 1)
#pragma unroll
            for (int r = 0; r < 4; ++r)
                rmax[r] = fmaxf(rmax[r], __shfl_xor(rmax[r], off, 64));

        float alpha[4], rsum[4];
#pragma unroll
        for (int r = 0; r < 4; ++r) {
            const float mnew = fmaxf(mrun[r], rmax[r]);
            alpha[r] = __expf(mrun[r] - mnew);
            mrun[r]  = mnew;
            rsum[r]  = 0.f;
        }
        __bf16* pw = &Ps[wave][0];
#pragma unroll
        for (int ni = 0; ni < 4; ++ni) {
#pragma unroll
            for (int r = 0; r < 4; ++r) {
                const float p = __expf(sacc[ni][r] - mrun[r]);
                rsum[r] += p;
                pw[(quad * 4 + r) * LDT + ni * 16 + l15] = (__bf16)p;
            }
        }
#pragma unroll
        for (int off = 1; off < 16; off <<= 1)
#pragma unroll
            for (int r = 0; r < 4; ++r)
                rsum[r] += __shfl_xor(rsum[r], off, 64);
#pragma unroll
        for (int r = 0; r < 4; ++r)
            lrun[r] = lrun[r] * alpha[r] + rsum[r];
#pragma unroll
        for (int nd = 0; nd < 4; ++nd)
#pragma unroll
            for (int r = 0; r < 4; ++r)
                oacc[nd][r] *= alpha[r];

        __syncthreads();

#pragma unroll
        for (int kk = 0; kk < 2; ++kk) {
            const int ko = kk * 32 + quad * 8;
            const bf16x8 ap = *(const bf16x8*)(pw + l15 * LDT + ko);
#pragma unroll
            for (int nd = 0; nd < 4; ++nd) {
                const bf16x8 bv = *(const bf16x8*)(Vt + (nd * 16 + l15) * LDT + ko);
                oacc[nd] = __builtin_amdgcn_mfma_f32_16x16x32_bf16(ap, bv, oacc[nd], 0, 0, 0);
            }
        }
    }

    float invl[4];
#pragma unroll
    for (int r = 0; r < 4; ++r) invl[r] = 1.0f / lrun[r];
#pragma unroll
    for (int nd = 0; nd < 4; ++nd) {
#pragma unroll
        for (int r = 0; r < 4; ++r) {
            const int trow = t0 + wave * 16 + quad * 4 + r;
            out[(size_t)(b * T_SZ + trow) * HID + h * DHEAD + nd * 16 + l15] =
                oacc[nd][r] * invl[r];
        }
    }
}

extern "C" void kernel_launch(void* const* d_in, const int* in_sizes, int n_in,
                              void* d_out, int out_size, void* d_ws, size_t ws_size,
                              hipStream_t stream) {
    const float* x   = (const float*)d_in[0];
    const float* enc = (const float*)d_in[1];
    const float* Wq  = (const float*)d_in[2];
    const float* bq  = (const float*)d_in[3];
    const float* Wk  = (const float*)d_in[4];
    const float* bk  = (const float*)d_in[5];
    const float* Wv  = (const float*)d_in[6];
    const float* bv  = (const float*)d_in[7];
    float* out = (float*)d_out;

    char* ws = (char*)d_ws;
    const size_t MiB = 1024 * 1024;
    __bf16* q_ws = (__bf16*)(ws);
    __bf16* k_ws = (__bf16*)(ws + 8 * MiB);
    __bf16* v_ws = (__bf16*)(ws + 16 * MiB);

    const dim3 blk(256);
    if (ws_size >= 46 * MiB) {
        __bf16* xb  = (__bf16*)(ws + 24 * MiB);
        __bf16* eb  = (__bf16*)(ws + 32 * MiB);
        __bf16* wqb = (__bf16*)(ws + 40 * MiB);
        __bf16* wkb = (__bf16*)(ws + 42 * MiB);
        __bf16* wvb = (__bf16*)(ws + 44 * MiB);
        cvt5_f32_bf16<<<dim3(5632), blk, 0, stream>>>(x, enc, Wq, Wk, Wv,
                                                      xb, eb, wqb, wkb, wvb);
        gemm3_bt_bias<<<dim3(8, 32, 3), blk, 0, stream>>>(
            xb, eb, wqb, wkb, wvb, bq, bk, bv, q_ws, k_ws, v_ws);
    } else {
        const dim3 gg(HID / 128, (B_SZ * T_SZ) / 128);
        gemm_bt_bias_f32in<<<gg, blk, 0, stream>>>(x,   Wq, bq, (__hip_bfloat16*)q_ws);
        gemm_bt_bias_f32in<<<gg, blk, 0, stream>>>(enc, Wk, bk, (__hip_bfloat16*)k_ws);
        gemm_bt_bias_f32in<<<gg, blk, 0, stream>>>(enc, Wv, bv, (__hip_bfloat16*)v_ws);
    }

    attn_flash_mfma<<<dim3(B_SZ * NHEADS * (T_SZ / 64)), blk, 0, stream>>>(
        q_ws, k_ws, v_ws, out);
}